// Round 2
// baseline (107.599 us; speedup 1.0000x reference)
//
#include <hip/hip_runtime.h>
#include <math.h>

#define THREADS 256

// 32 magnitude patterns of the D4 codebook, 2-bit codes per coordinate:
// c in {0,1,2}  =>  |g_i| = 0.5 + c.   mc = c0 | c1<<2 | c2<<4 | c3<<6
// Pattern order is exactly the reference's i8 = 0..31 enumeration.
#define MCP_LIST \
  0x00, 0x55, 0x50, 0x05, 0x44, 0x11, 0x14, 0x41, \
  0x01, 0x04, 0x10, 0x40, 0x54, 0x51, 0x45, 0x15, \
  0x02, 0x08, 0x20, 0x80, 0x09, 0x06, 0x12, 0x42, \
  0x21, 0x24, 0x18, 0x48, 0x81, 0x84, 0x90, 0x60

__device__ const unsigned d_MCP[32] = { MCP_LIST };   // runtime-indexed copy
constexpr unsigned h_MCP[32] = { MCP_LIST };           // compile-time folded copy

// Fast path: exact real-arithmetic argmax in f64 + rigorous uncertainty gap.
// If the top-2 true scores are closer than the worst-case f32 rounding of the
// numpy reference's score computation, flag the vector for exact re-check.
__global__ __launch_bounds__(THREADS)
void d4_fast_kernel(const float* __restrict__ X, float* __restrict__ out,
                    unsigned char* __restrict__ flags, int n)
{
    const int i = blockIdx.x * blockDim.x + threadIdx.x;
    if (i >= n) return;

    const float4 xv = reinterpret_cast<const float4*>(X)[i];
    const float fx0 = xv.x, fx1 = xv.y, fx2 = xv.z, fx3 = xv.w;

    const double a0 = fabs((double)fx0), a1 = fabs((double)fx1);
    const double a2 = fabs((double)fx2), a3 = fabs((double)fx3);
    const double u0 = a0 + a0, u1 = a1 + a1, u2 = a2 + a2, u3 = a3 + a3; // 2a
    const double v0 = u0 + u0, v1 = u1 + u1, v2 = u2 + u2, v3 = u3 + u3; // 4a
    const double h0 = 0.5 * a0, h1 = 0.5 * a1, h2 = 0.5 * a2, h3 = 0.5 * a3;
    const double t0 = h0 + a0, t1 = h1 + a1, t2 = h2 + a2, t3 = h3 + a3;  // 1.5a
    const double w0 = t0 + a0, w1 = t1 + a1, w2 = t2 + a2, w3 = t3 + a3;  // 2.5a
    const double A = (a0 + a1) + (a2 + a3);

    const int s0 = (fx0 < 0.f) ? 1 : 0, s1 = (fx1 < 0.f) ? 1 : 0;
    const int s2 = (fx2 < 0.f) ? 1 : 0, s3 = (fx3 < 0.f) ? 1 : 0;
    const int qp = (s0 + s1 + s2 + s3) & 1;   // parity of # negative coords

    double best = -1e300, second = -1e300;
    int bi = 0;
#pragma unroll
    for (int p = 0; p < 32; ++p) {
        const unsigned mc = h_MCP[p];
        const int c0 = mc & 3, c1 = (mc >> 2) & 3, c2 = (mc >> 4) & 3, c3 = (mc >> 6) & 3;
        const int nsq = 1 + c0 * (c0 + 1) + c1 * (c1 + 1) + c2 * (c2 + 1) + c3 * (c3 + 1);

        double s = A - (double)nsq;           // 2*sum(m_i*a_i) - |m|^2
        if (c0 == 1) s += u0; else if (c0 == 2) s += v0;
        if (c1 == 1) s += u1; else if (c1 == 2) s += v1;
        if (c2 == 1) s += u2; else if (c2 == 2) s += v2;
        if (c3 == 1) s += u3; else if (c3 == 2) s += v3;

        const double q0 = (c0 == 0) ? h0 : ((c0 == 1) ? t0 : w0);
        const double q1 = (c1 == 0) ? h1 : ((c1 == 1) ? t1 : w1);
        const double q2 = (c2 == 0) ? h2 : ((c2 == 1) ? t2 : w2);
        const double q3 = (c3 == 0) ? h3 : ((c3 == 1) ? t3 : w3);
        const double minp = fmin(fmin(q0, q1), fmin(q2, q3));

        const int rp = (c0 + c1 + c2 + c3) & 1;         // required minus-parity
        const double eff = (rp != qp) ? (s - 4.0 * minp) : s;

        if (eff > best) { second = best; best = eff; bi = p; }
        else if (eff > second) { second = eff; }
    }

    // ---- reconstruct winning codeword + its reference index ----
    const unsigned mc = d_MCP[bi];
    const int c0 = mc & 3, c1 = (mc >> 2) & 3, c2 = (mc >> 4) & 3, c3 = (mc >> 6) & 3;
    const int rp = (c0 + c1 + c2 + c3) & 1;
    const bool flip = (rp != qp);

    const double p0 = (c0 == 0) ? h0 : ((c0 == 1) ? t0 : w0);
    const double p1 = (c1 == 0) ? h1 : ((c1 == 1) ? t1 : w1);
    const double p2 = (c2 == 0) ? h2 : ((c2 == 1) ? t2 : w2);
    const double p3 = (c3 == 0) ? h3 : ((c3 == 1) ? t3 : w3);
    int f = 0; double mp = p0;
    if (p1 < mp) { mp = p1; f = 1; }
    if (p2 < mp) { mp = p2; f = 2; }
    if (p3 < mp) { mp = p3; f = 3; }

    // two smallest of {p0..p3} via min/max network (for the gap bound)
    const double m01 = fmin(p0, p1), M01 = fmax(p0, p1);
    const double m23 = fmin(p2, p3), M23 = fmax(p2, p3);
    const double q1v = fmin(m01, m23);
    const double q2v = fmin(fmax(m01, m23), fmin(M01, M23));

    // runner-up within the winning pattern:
    //  parity mismatch: second-best single flip  -> cost gap 4*(q2-q1)
    //  parity match:    cheapest double flip     -> cost 4*(q1+q2)
    const double within = flip ? 4.0 * (q2v - q1v) : 4.0 * (q1v + q2v);
    const double gap = fmin(best - second, within);
    // rigorous bound on 2x worst-case f32 rounding of the reference scores
    const double delta = 4e-6 * (A + 1.0);
    flags[i] = (gap < delta) ? 1 : 0;

    const bool n0 = ((s0 != 0) != (flip && f == 0));
    const bool n1 = ((s1 != 0) != (flip && f == 1));
    const bool n2 = ((s2 != 0) != (flip && f == 2));
    const bool n3 = ((s3 != 0) != (flip && f == 3));

    const float m0 = 0.5f + (float)c0, m1 = 0.5f + (float)c1;
    const float m2 = 0.5f + (float)c2, m3 = 0.5f + (float)c3;
    float4 g;
    g.x = n0 ? -m0 : m0;
    g.y = n1 ? -m1 : m1;
    g.z = n2 ? -m2 : m2;
    g.w = n3 ? -m3 : m3;

    // invert _code3_signs: b7 = sign(g0), b6 = sign(g1)^b7, b5 = sign(g2)^b7
    const int b7 = n0 ? 1 : 0;
    const int b6 = (n1 ? 1 : 0) ^ b7;
    const int b5 = (n2 ? 1 : 0) ^ b7;
    const int idx = bi | (b5 << 5) | (b6 << 6) | (b7 << 7);

    reinterpret_cast<float4*>(out)[i] = g;                 // output 0: grid[idx]
    out[(size_t)4 * (size_t)n + (size_t)i] = (float)idx;   // output 1: idx (as f32)
}

// Slow path: bit-exact emulation of the numpy reference for flagged vectors.
// scores[k] = f32(2*f32dot(x, g_k)) - gn_k, sequential rounding, no FMA;
// argmax with first-wins tie-break.
__global__ __launch_bounds__(THREADS)
void d4_exact_kernel(const float* __restrict__ X,
                     const float* __restrict__ grid,
                     const float* __restrict__ gnorm,
                     float* __restrict__ out,
                     const unsigned char* __restrict__ flags, int n)
{
    const int i = blockIdx.x * blockDim.x + threadIdx.x;
    if (i >= n) return;
    if (!flags[i]) return;

    const float4 xv = reinterpret_cast<const float4*>(X)[i];
    float best = -INFINITY;
    int bk = 0;
    for (int k = 0; k < 256; ++k) {
        const float g0 = grid[4 * k + 0], g1 = grid[4 * k + 1];
        const float g2 = grid[4 * k + 2], g3 = grid[4 * k + 3];
        float d = __fmul_rn(xv.x, g0);
        d = __fadd_rn(d, __fmul_rn(xv.y, g1));
        d = __fadd_rn(d, __fmul_rn(xv.z, g2));
        d = __fadd_rn(d, __fmul_rn(xv.w, g3));
        const float s = __fsub_rn(__fmul_rn(2.0f, d), gnorm[k]);
        if (s > best) { best = s; bk = k; }
    }
    float4 g;
    g.x = grid[4 * bk + 0]; g.y = grid[4 * bk + 1];
    g.z = grid[4 * bk + 2]; g.w = grid[4 * bk + 3];
    reinterpret_cast<float4*>(out)[i] = g;
    out[(size_t)4 * (size_t)n + (size_t)i] = (float)bk;
}

extern "C" void kernel_launch(void* const* d_in, const int* in_sizes, int n_in,
                              void* d_out, int out_size, void* d_ws, size_t ws_size,
                              hipStream_t stream)
{
    const float* X = (const float*)d_in[0];
    const float* grid = (const float*)d_in[1];
    const float* gnorm = (const float*)d_in[2];
    float* out = (float*)d_out;
    unsigned char* flags = (unsigned char*)d_ws;
    const int n = in_sizes[0] / 4;
    const int blocks = (n + THREADS - 1) / THREADS;
    hipLaunchKernelGGL(d4_fast_kernel, dim3(blocks), dim3(THREADS), 0, stream,
                       X, out, flags, n);
    hipLaunchKernelGGL(d4_exact_kernel, dim3(blocks), dim3(THREADS), 0, stream,
                       X, grid, gnorm, out, flags, n);
}

// Round 3
// 89.689 us; speedup vs baseline: 1.1997x; 1.1997x over previous
//
#include <hip/hip_runtime.h>
#include <math.h>

#define THREADS 256

// 32 magnitude patterns of the D4 codebook, 2-bit codes per coordinate:
// c in {0,1,2}  =>  |g_i| = 0.5 + c.   mc = c0 | c1<<2 | c2<<4 | c3<<6
// Pattern order is exactly the reference's i8 = 0..31 enumeration.
// Score identity: s_p = (A-1) + sum_{c_i=1}(2a_i-2) + sum_{c_i=2}(4a_i-6).
#define MCP_LIST \
  0x00, 0x55, 0x50, 0x05, 0x44, 0x11, 0x14, 0x41, \
  0x01, 0x04, 0x10, 0x40, 0x54, 0x51, 0x45, 0x15, \
  0x02, 0x08, 0x20, 0x80, 0x09, 0x06, 0x12, 0x42, \
  0x21, 0x24, 0x18, 0x48, 0x81, 0x84, 0x90, 0x60

__device__ const unsigned d_MCP[32] = { MCP_LIST };   // runtime-indexed copy
constexpr unsigned h_MCP[32] = { MCP_LIST };           // compile-time folded copy

__global__ __launch_bounds__(THREADS)
void d4_fused_kernel(const float* __restrict__ X,
                     const float* __restrict__ grid,
                     const float* __restrict__ gnorm,
                     float* __restrict__ out, int n)
{
    // Stage codebook for the (rare) exact slow path; broadcast reads later.
    __shared__ float4 sgrid[256];
    __shared__ float  sgn[256];
    sgrid[threadIdx.x] = reinterpret_cast<const float4*>(grid)[threadIdx.x];
    sgn[threadIdx.x]   = gnorm[threadIdx.x];
    __syncthreads();

    const int i = blockIdx.x * blockDim.x + threadIdx.x;
    if (i >= n) return;

    const float4 xv = reinterpret_cast<const float4*>(X)[i];
    const float fx0 = xv.x, fx1 = xv.y, fx2 = xv.z, fx3 = xv.w;

    const float a0 = fabsf(fx0), a1 = fabsf(fx1), a2 = fabsf(fx2), a3 = fabsf(fx3);
    // exact: u = 2a, v = 4a
    const float r0 = (a0 + a0) - 2.f, r1 = (a1 + a1) - 2.f;
    const float r2 = (a2 + a2) - 2.f, r3 = (a3 + a3) - 2.f;
    const float z0 = (a0 + a0 + a0 + a0) - 6.f, z1 = (a1 + a1 + a1 + a1) - 6.f;
    const float z2 = (a2 + a2 + a2 + a2) - 6.f, z3 = (a3 + a3 + a3 + a3) - 6.f;
    const float A = (a0 + a1) + (a2 + a3);
    const float base = A - 1.f;

    // magnitude-weighted "flip costs" m_i * a_i for the 3 levels
    const float h0 = 0.5f * a0, h1 = 0.5f * a1, h2 = 0.5f * a2, h3 = 0.5f * a3;
    const float t0 = h0 + a0, t1 = h1 + a1, t2 = h2 + a2, t3 = h3 + a3;  // 1.5a
    const float w0 = t0 + a0, w1 = t1 + a1, w2 = t2 + a2, w3 = t3 + a3;  // 2.5a

    const int s0 = (fx0 < 0.f) ? 1 : 0, s1 = (fx1 < 0.f) ? 1 : 0;
    const int s2 = (fx2 < 0.f) ? 1 : 0, s3 = (fx3 < 0.f) ? 1 : 0;
    const int qp = (s0 + s1 + s2 + s3) & 1;   // parity of # negative coords

    float best = -1e30f, second = -1e30f;
    int bi = 0;
#pragma unroll
    for (int p = 0; p < 32; ++p) {
        const unsigned mc = h_MCP[p];
        const int c0 = mc & 3, c1 = (mc >> 2) & 3, c2 = (mc >> 4) & 3, c3 = (mc >> 6) & 3;

        float s = base;
        if (c0 == 1) s += r0; else if (c0 == 2) s += z0;
        if (c1 == 1) s += r1; else if (c1 == 2) s += z1;
        if (c2 == 1) s += r2; else if (c2 == 2) s += z2;
        if (c3 == 1) s += r3; else if (c3 == 2) s += z3;

        const float q0 = (c0 == 0) ? h0 : ((c0 == 1) ? t0 : w0);
        const float q1 = (c1 == 0) ? h1 : ((c1 == 1) ? t1 : w1);
        const float q2 = (c2 == 0) ? h2 : ((c2 == 1) ? t2 : w2);
        const float q3 = (c3 == 0) ? h3 : ((c3 == 1) ? t3 : w3);
        const float minp = fminf(fminf(q0, q1), fminf(q2, q3));

        const int rp = (c0 + c1 + c2 + c3) & 1;         // required minus-parity
        const float eff = (rp != qp) ? (s - 4.f * minp) : s;

        if (eff > best) { second = best; best = eff; bi = p; }
        else if (eff > second) { second = eff; }
    }

    // ---- reconstruct winning codeword + its reference index ----
    {
        const unsigned mc = d_MCP[bi];
        const int c0 = mc & 3, c1 = (mc >> 2) & 3, c2 = (mc >> 4) & 3, c3 = (mc >> 6) & 3;
        const int rp = (c0 + c1 + c2 + c3) & 1;
        const bool flip = (rp != qp);

        const float p0 = (c0 == 0) ? h0 : ((c0 == 1) ? t0 : w0);
        const float p1 = (c1 == 0) ? h1 : ((c1 == 1) ? t1 : w1);
        const float p2 = (c2 == 0) ? h2 : ((c2 == 1) ? t2 : w2);
        const float p3 = (c3 == 0) ? h3 : ((c3 == 1) ? t3 : w3);
        int f = 0; float mp = p0;
        if (p1 < mp) { mp = p1; f = 1; }
        if (p2 < mp) { mp = p2; f = 2; }
        if (p3 < mp) { mp = p3; f = 3; }

        // two smallest of {p0..p3} (for the within-pattern runner-up bound)
        const float m01 = fminf(p0, p1), M01 = fmaxf(p0, p1);
        const float m23 = fminf(p2, p3), M23 = fmaxf(p2, p3);
        const float q1v = fminf(m01, m23);
        const float q2v = fminf(fmaxf(m01, m23), fminf(M01, M23));

        // runner-up within the winning pattern:
        //  parity mismatch: second-best single flip  -> cost gap 4*(q2-q1)
        //  parity match:    cheapest double flip     -> cost 4*(q1+q2)
        const float within = flip ? 4.f * (q2v - q1v) : 4.f * (q1v + q2v);
        const float gap = fminf(best - second, within);
        // covers worst-case f32 rounding of BOTH my scores and the numpy
        // reference's (each <= ~7e-7*(5A+27)); >2x safety margin
        const float delta = 8e-6f * (A + 6.f);

        const bool n0 = ((s0 != 0) != (flip && f == 0));
        const bool n1 = ((s1 != 0) != (flip && f == 1));
        const bool n2 = ((s2 != 0) != (flip && f == 2));
        const bool n3 = ((s3 != 0) != (flip && f == 3));

        const float m0 = 0.5f + (float)c0, m1 = 0.5f + (float)c1;
        const float m2 = 0.5f + (float)c2, m3 = 0.5f + (float)c3;
        float4 g;
        g.x = n0 ? -m0 : m0;
        g.y = n1 ? -m1 : m1;
        g.z = n2 ? -m2 : m2;
        g.w = n3 ? -m3 : m3;

        // invert _code3_signs: b7=sign(g0), b6=sign(g1)^b7, b5=sign(g2)^b7
        const int b7 = n0 ? 1 : 0;
        const int b6 = (n1 ? 1 : 0) ^ b7;
        const int b5 = (n2 ? 1 : 0) ^ b7;
        int idx = bi | (b5 << 5) | (b6 << 6) | (b7 << 7);

        if (gap < delta) {
            // Rare (~2e-4): bit-exact emulation of the numpy reference.
            // Sequential f32 dot (no FMA), 2*dot - gn, first-wins argmax.
            float bexact = -INFINITY;
            int bk = 0;
            for (int k = 0; k < 256; ++k) {
                const float4 gk = sgrid[k];
                float d = __fmul_rn(fx0, gk.x);
                d = __fadd_rn(d, __fmul_rn(fx1, gk.y));
                d = __fadd_rn(d, __fmul_rn(fx2, gk.z));
                d = __fadd_rn(d, __fmul_rn(fx3, gk.w));
                const float sc = __fsub_rn(__fmul_rn(2.0f, d), sgn[k]);
                if (sc > bexact) { bexact = sc; bk = k; }
            }
            g = sgrid[bk];
            idx = bk;
        }

        reinterpret_cast<float4*>(out)[i] = g;                 // output 0
        out[(size_t)4 * (size_t)n + (size_t)i] = (float)idx;   // output 1
    }
}

extern "C" void kernel_launch(void* const* d_in, const int* in_sizes, int n_in,
                              void* d_out, int out_size, void* d_ws, size_t ws_size,
                              hipStream_t stream)
{
    const float* X = (const float*)d_in[0];
    const float* grid = (const float*)d_in[1];
    const float* gnorm = (const float*)d_in[2];
    float* out = (float*)d_out;
    const int n = in_sizes[0] / 4;
    const int blocks = (n + THREADS - 1) / THREADS;
    hipLaunchKernelGGL(d4_fused_kernel, dim3(blocks), dim3(THREADS), 0, stream,
                       X, grid, gnorm, out, n);
}